// Round 1
// baseline (1067.858 us; speedup 1.0000x reference)
//
#include <hip/hip_runtime.h>
#include <hip/hip_bf16.h>

// HyperNetSIR: x(N,3) f32, H(E,N) f32 0/1 mask (density 0.002), beta(N), gamma(N), steps(int)
// out: (steps, N, 3) f32 trajectory.
//
// Strategy: extract sparse adjacency from H once per launch (H is restored
// from pristine each timed call, so the 400MB scan is unavoidable), then run
// steps-1 cheap sparse SpMV+pointwise steps.

#define EDGE_CAP 96   // max nodes per edge (mean 40, sigma 6.3 -> ~9 sigma headroom)
#define NODE_CAP 32   // max edges per node (mean 10, sigma 3.2 -> ~7 sigma headroom)

__global__ void zero_counts_kernel(int* edge_cnt, int* node_cnt, int n_edges, int n_nodes) {
    int i = blockIdx.x * blockDim.x + threadIdx.x;
    if (i < n_edges) edge_cnt[i] = 0;
    if (i < n_nodes) node_cnt[i] = 0;
}

// One block per edge row. Scan the row of H with float4 loads, append nonzero
// column indices to edge_nodes[e], and append e to node_edges[col] (atomics).
__global__ void build_adjacency_kernel(const float* __restrict__ H,
                                       int* __restrict__ edge_cnt,
                                       int* __restrict__ edge_nodes,
                                       int* __restrict__ node_cnt,
                                       int* __restrict__ node_edges,
                                       int n_nodes) {
    const int e = blockIdx.x;
    const float* row = H + (size_t)e * n_nodes;
    const int n4 = n_nodes >> 2;
    const float4* row4 = (const float4*)row;
    for (int c4 = threadIdx.x; c4 < n4; c4 += blockDim.x) {
        float4 v = row4[c4];
        int cbase = c4 << 2;
        if (v.x != 0.0f) {
            int p = atomicAdd(&edge_cnt[e], 1);
            if (p < EDGE_CAP) edge_nodes[e * EDGE_CAP + p] = cbase;
            int q = atomicAdd(&node_cnt[cbase], 1);
            if (q < NODE_CAP) node_edges[cbase * NODE_CAP + q] = e;
        }
        if (v.y != 0.0f) {
            int c = cbase + 1;
            int p = atomicAdd(&edge_cnt[e], 1);
            if (p < EDGE_CAP) edge_nodes[e * EDGE_CAP + p] = c;
            int q = atomicAdd(&node_cnt[c], 1);
            if (q < NODE_CAP) node_edges[c * NODE_CAP + q] = e;
        }
        if (v.z != 0.0f) {
            int c = cbase + 2;
            int p = atomicAdd(&edge_cnt[e], 1);
            if (p < EDGE_CAP) edge_nodes[e * EDGE_CAP + p] = c;
            int q = atomicAdd(&node_cnt[c], 1);
            if (q < NODE_CAP) node_edges[c * NODE_CAP + q] = e;
        }
        if (v.w != 0.0f) {
            int c = cbase + 3;
            int p = atomicAdd(&edge_cnt[e], 1);
            if (p < EDGE_CAP) edge_nodes[e * EDGE_CAP + p] = c;
            int q = atomicAdd(&node_cnt[c], 1);
            if (q < NODE_CAP) node_edges[c * NODE_CAP + q] = e;
        }
    }
    // tail (n_nodes not multiple of 4)
    if (threadIdx.x == 0) {
        for (int c = n4 << 2; c < n_nodes; ++c) {
            if (row[c] != 0.0f) {
                int p = atomicAdd(&edge_cnt[e], 1);
                if (p < EDGE_CAP) edge_nodes[e * EDGE_CAP + p] = c;
                int q = atomicAdd(&node_cnt[c], 1);
                if (q < NODE_CAP) node_edges[c * NODE_CAP + q] = e;
            }
        }
    }
}

// traj[0] = x; unpack state columns S,I,R.
__global__ void init_state_kernel(const float* __restrict__ x,
                                  float* __restrict__ S, float* __restrict__ I,
                                  float* __restrict__ R, float* __restrict__ out0,
                                  int n_nodes) {
    int n = blockIdx.x * blockDim.x + threadIdx.x;
    if (n >= n_nodes) return;
    float s = x[n * 3 + 0], iv = x[n * 3 + 1], r = x[n * 3 + 2];
    S[n] = s; I[n] = iv; R[n] = r;
    out0[n * 3 + 0] = s; out0[n * 3 + 1] = iv; out0[n * 3 + 2] = r;
}

// y[e] = sum_{n in edge e} I[n].  One wave (64 lanes) per edge.
__global__ void edge_sum_kernel(const int* __restrict__ edge_cnt,
                                const int* __restrict__ edge_nodes,
                                const float* __restrict__ I,
                                float* __restrict__ y, int n_edges) {
    int wavesPerBlock = blockDim.x >> 6;
    int e = blockIdx.x * wavesPerBlock + (threadIdx.x >> 6);
    int lane = threadIdx.x & 63;
    if (e >= n_edges) return;
    int cnt = min(edge_cnt[e], EDGE_CAP);
    float s = 0.0f;
    for (int i = lane; i < cnt; i += 64) s += I[edge_nodes[e * EDGE_CAP + i]];
    #pragma unroll
    for (int off = 32; off > 0; off >>= 1) s += __shfl_down(s, off, 64);
    if (lane == 0) y[e] = s;
}

// z[n] = sum_{e ni n} y[e]; SIR update + clamp + renormalize; write traj slice.
__global__ void node_update_kernel(const int* __restrict__ node_cnt,
                                   const int* __restrict__ node_edges,
                                   const float* __restrict__ y,
                                   const float* __restrict__ beta,
                                   const float* __restrict__ gamma,
                                   float* __restrict__ S, float* __restrict__ I,
                                   float* __restrict__ R, float* __restrict__ out_t,
                                   int n_nodes) {
    int n = blockIdx.x * blockDim.x + threadIdx.x;
    if (n >= n_nodes) return;
    int cnt = min(node_cnt[n], NODE_CAP);
    float z = 0.0f;
    for (int i = 0; i < cnt; ++i) z += y[node_edges[n * NODE_CAP + i]];
    float s = S[n], iv = I[n], r = R[n];
    float nc = beta[n] * s * z;
    float nr = gamma[n] * iv;
    float s2 = fmaxf(s - nc, 0.0f);
    float i2 = fmaxf(iv + nc - nr, 0.0f);
    float r2 = fmaxf(r + nr, 0.0f);
    float inv = 1.0f / (s2 + i2 + r2);
    s2 *= inv; i2 *= inv; r2 *= inv;
    S[n] = s2; I[n] = i2; R[n] = r2;
    out_t[n * 3 + 0] = s2; out_t[n * 3 + 1] = i2; out_t[n * 3 + 2] = r2;
}

extern "C" void kernel_launch(void* const* d_in, const int* in_sizes, int n_in,
                              void* d_out, int out_size, void* d_ws, size_t ws_size,
                              hipStream_t stream) {
    const float* x     = (const float*)d_in[0];
    const float* H     = (const float*)d_in[1];
    const float* beta  = (const float*)d_in[2];
    const float* gamma = (const float*)d_in[3];
    float* out = (float*)d_out;

    const int n_nodes = in_sizes[0] / 3;                 // 20000
    const int n_edges = in_sizes[1] / n_nodes;           // 5000
    const int steps   = out_size / in_sizes[0];          // 50

    // workspace carve-up (ints/floats are both 4B)
    char* ws = (char*)d_ws;
    int*   edge_cnt   = (int*)ws;                         ws += (size_t)n_edges * 4;
    int*   node_cnt   = (int*)ws;                         ws += (size_t)n_nodes * 4;
    int*   edge_nodes = (int*)ws;                         ws += (size_t)n_edges * EDGE_CAP * 4;
    int*   node_edges = (int*)ws;                         ws += (size_t)n_nodes * NODE_CAP * 4;
    float* y          = (float*)ws;                       ws += (size_t)n_edges * 4;
    float* S          = (float*)ws;                       ws += (size_t)n_nodes * 4;
    float* I          = (float*)ws;                       ws += (size_t)n_nodes * 4;
    float* R          = (float*)ws;                       ws += (size_t)n_nodes * 4;

    // 1. zero adjacency counters (ws is poisoned 0xAA each call)
    {
        int mx = max(n_edges, n_nodes);
        zero_counts_kernel<<<(mx + 255) / 256, 256, 0, stream>>>(edge_cnt, node_cnt, n_edges, n_nodes);
    }
    // 2. extract sparsity of H (the one unavoidable 400MB scan)
    build_adjacency_kernel<<<n_edges, 256, 0, stream>>>(H, edge_cnt, edge_nodes,
                                                        node_cnt, node_edges, n_nodes);
    // 3. init state + traj[0]
    init_state_kernel<<<(n_nodes + 255) / 256, 256, 0, stream>>>(x, S, I, R, out, n_nodes);

    // 4. sparse SIR steps
    const int wavesPerBlock = 4;  // 256 threads
    const int edgeGrid = (n_edges + wavesPerBlock - 1) / wavesPerBlock;
    for (int t = 1; t < steps; ++t) {
        edge_sum_kernel<<<edgeGrid, 256, 0, stream>>>(edge_cnt, edge_nodes, I, y, n_edges);
        node_update_kernel<<<(n_nodes + 255) / 256, 256, 0, stream>>>(
            node_cnt, node_edges, y, beta, gamma, S, I, R,
            out + (size_t)t * n_nodes * 3, n_nodes);
    }
}